// Round 11
// baseline (101.231 us; speedup 1.0000x reference)
//
#include <hip/hip_runtime.h>
#include <stdint.h>
#include <stddef.h>

// AdderNet 2D: out[n,f,i,j] = -sum_{c,kh,kw} |xpad[n,c,i+kh,j+kw] - W[f,c,kh,kw]|
// x: [16,32,56,56] f32, W: [64,32,3,3] f32, out: [16,64,56,56] f32. PAD=1, STRIDE=1.
//
// R11 = R10 (wave = 4 rows x 56 cols x 2 filters, w-in-LDS, x via per-row buffer
// SRDs with HW OOB-zero == zero-pad) + two fixes:
//  (1) asm keepalives pin wv (4xb128+b64) and xv in VGPRs -- R10's VGPR=36 proved
//      the compiler rematerialized w as ~18 serial ds_read_b32/ch (LDS pipe 1.45x
//      over VALU, the R6/R8/R9/R10 recurring disease).
//  (2) XCD-aware bid remap: the 8 fo-blocks sharing one (n,rg) x-tile go to the
//      SAME XCD (bid = fo*224+g, 224%8==0) -> x L2-resident per XCD
//      (R10 FETCH=25MB = 4x over-fetch from cross-XCD round-robin).

#define N_   16
#define C_   32
#define H_   56
#define F_   64
#define HW_  3136
#define ROWS 4
#define ROWB 224
#define TPB  256
#define WSTR 20          // floats per filter-pair slot (18 used; 80B stride keeps 16B align)
#define NG   (N_ * (H_ / ROWS))   // 224 (n,rowgroup) tiles

typedef int   int32x4 __attribute__((ext_vector_type(4)));
typedef float f32x4   __attribute__((ext_vector_type(4)));
typedef float f32x2   __attribute__((ext_vector_type(2)));

__device__ float __buf_load_f32(int32x4 srsrc, int voffset, int soffset, int aux) __asm("llvm.amdgcn.raw.buffer.load.f32");

__device__ inline int32x4 make_srd(const void* p, int bytes) {
    union { const void* p; uint32_t u[2]; } a; a.p = p;
    int32x4 r;
    r.x = (int)a.u[0];
    r.y = (int)a.u[1];        // VA < 2^48, high bits 0 -> stride field 0
    r.z = bytes;              // num_records (stride==0 -> bytes)
    r.w = 0x00020000;         // raw untyped dword
    return r;
}

__global__ __launch_bounds__(TPB, 7)   // 7 waves/EU -> VGPR cap 72 (est. ~65, watch scratch)
void adder_main(const float* __restrict__ x,
                const float* __restrict__ w,
                float* __restrict__ out) {
    // lds_w[(c*8+q)*20 + p*9 + kk] = W[(fo*8 + q*2 + p)*288 + c*9 + kk]
    __shared__ __align__(16) float lds_w[C_ * 8 * WSTR];   // 20480 B

    const int tid  = threadIdx.x;
    const int lane = tid & 63;
    const int bid  = blockIdx.x;
    // XCD-aware decode: fo slowest -> the 8 fo-blocks of one g are 224 apart,
    // 224%8==0 -> same XCD -> shared x tile is L2-local.
    const int fo   = bid / NG;                // filter octet 0..7
    const int g    = bid % NG;                // (n, rowgroup) tile
    const int rg   = g % (H_ / ROWS);
    const int n    = g / (H_ / ROWS);
    const int row0 = rg * ROWS;

    // ---- stage 8 filters' weights, transposed to [c][q(pair)][p][kk] ----
    for (int e = tid; e < C_ * 8 * 18; e += TPB) {
        const int c = e / 144;
        const int r = e % 144;
        const int q_ = r / 18;
        const int s  = r % 18;          // p*9 + kk
        const int p_ = s / 9;
        const int kk = s % 9;
        lds_w[(c * 8 + q_) * WSTR + s] = w[((fo * 8 + q_ * 2 + p_) * C_ + c) * 9 + kk];
    }
    __syncthreads();

    const int q = __builtin_amdgcn_readfirstlane(tid >> 6);   // wave's filter pair 0..3

    const int vA = (lane - 1) * 4;   // col j-1 (lane 0 -> 0xFFFFFFFC -> HW OOB zero)
    const int vB = lane * 4;         // col j   (+soffset 4 -> col j+1)

    // 6 x row-slots: slot s <-> image row row0-1+s; validity wave-uniform
    const int nr0 = (row0 >= 1)          ? ROWB : 0;
    const int nr5 = (row0 + 4 <= H_ - 1) ? ROWB : 0;

    const float* xbase = x + (size_t)n * C_ * HW_ + (ptrdiff_t)(row0 - 1) * H_;

    float acc[2][ROWS];
#pragma unroll
    for (int p = 0; p < 2; ++p)
#pragma unroll
        for (int r = 0; r < ROWS; ++r) acc[p][r] = 0.0f;

    float xv[6][3];

#pragma unroll 1
    for (int c = 0; c < C_; ++c) {
        // 18 x loads (6 rows x 3 taps), coalesced, OOB rows/cols return 0
        const float* bp = xbase + (size_t)c * HW_;
#pragma unroll
        for (int s = 0; s < 6; ++s) {
            const int nr = (s == 0) ? nr0 : (s == 5) ? nr5 : ROWB;
            int32x4 srd = make_srd(bp + s * H_, nr);
            xv[s][0] = __buf_load_f32(srd, vA, 0, 0);
            xv[s][1] = __buf_load_f32(srd, vB, 0, 0);
            xv[s][2] = __buf_load_f32(srd, vB, 4, 0);
        }

        // this pair's 18 w floats: 4x b128 + 1x b64 broadcast reads, PINNED in VGPRs
        const float* wp = &lds_w[(c * 8 + q) * WSTR];
        f32x4 wv0 = *(const f32x4*)(wp);
        f32x4 wv1 = *(const f32x4*)(wp + 4);
        f32x4 wv2 = *(const f32x4*)(wp + 8);
        f32x4 wv3 = *(const f32x4*)(wp + 12);
        f32x2 wv4 = *(const f32x2*)(wp + 16);
        asm volatile("" : "+v"(wv0), "+v"(wv1), "+v"(wv2), "+v"(wv3), "+v"(wv4));

        // pin xv too (forces the 18 loads to stay issued-upfront, one vmcnt drain)
#pragma unroll
        for (int s = 0; s < 6; ++s) {
            asm volatile("" : "+v"(xv[s][0]), "+v"(xv[s][1]), "+v"(xv[s][2]));
        }

#pragma unroll
        for (int p = 0; p < 2; ++p) {
#pragma unroll
            for (int kh = 0; kh < 3; ++kh) {
#pragma unroll
                for (int kw = 0; kw < 3; ++kw) {
                    const int i = p * 9 + kh * 3 + kw;
                    const float wf = (i < 4)  ? wv0[i]
                                   : (i < 8)  ? wv1[i - 4]
                                   : (i < 12) ? wv2[i - 8]
                                   : (i < 16) ? wv3[i - 12]
                                   :            wv4[i - 16];
#pragma unroll
                    for (int r = 0; r < ROWS; ++r)
                        acc[p][r] += fabsf(xv[r + kh][kw] - wf);
                }
            }
        }
    }

    if (lane < H_) {
#pragma unroll
        for (int p = 0; p < 2; ++p)
#pragma unroll
            for (int r = 0; r < ROWS; ++r)
                out[(size_t)(n * F_ + fo * 8 + q * 2 + p) * HW_ + (row0 + r) * H_ + lane] = -acc[p][r];
    }
}

extern "C" void kernel_launch(void* const* d_in, const int* in_sizes, int n_in,
                              void* d_out, int out_size, void* d_ws, size_t ws_size,
                              hipStream_t stream) {
    const float* x = (const float*)d_in[0];
    const float* w = (const float*)d_in[1];
    float* out = (float*)d_out;
    adder_main<<<dim3(8 * NG), dim3(TPB), 0, stream>>>(x, w, out);
}